// Round 8
// baseline (811.248 us; speedup 1.0000x reference)
//
#include <hip/hip_runtime.h>
#include <hip/hip_bf16.h>
#include <cstdint>

// Shapes: B=512, S=196, I=2048, Q=1024, H=512
// ques_attn == ques_feat exactly (softmax over singleton axis). Only img_attn computed:
//   cc[b][h]  = sum_q qf[b][q]*w2g[q][h] + b2g[h] + b2x[h]
//   score[r]  = sum_h tanh( sum_k X[r][k]*w2x[k][h] + cc[b(r)][h] ) * w2h[h]   (r = b*196+s)
//   a = softmax_s(score);  img_attn[b][f] = sum_s a[b][s] * X[b][s][f]
//
// r8: BM=128 (halves B L2-traffic to 1.6GB, the unmodeled tax), 8 waves with
// wave = 128 rows x 64 cols (acc 128 AGPR, ~212 unified regs, 8 waves/CU).
// Pipeline with PROVABLE in-order-vmcnt distances: B(t+1) reg-dbuf issued at
// step top (so waiting on B(t) never forces a fresh DMA), DMA distance 2 over
// 3 LDS buffers, one literal vmcnt(10) per step (retires exactly DMA(t+1),
// keeps B(t+1)+DMA(t+2) in flight across raw s_barrier). Zero full drains.

typedef __attribute__((ext_vector_type(8))) short bf16x8;
typedef __attribute__((ext_vector_type(4))) float f32x4;

typedef __attribute__((address_space(1))) const unsigned int as1_uint;
typedef __attribute__((address_space(3))) unsigned int as3_uint;

__device__ inline unsigned short f2bf(float f) {
    union { float f; unsigned u; } v; v.f = f;
    unsigned u = v.u;
    u += 0x7FFFu + ((u >> 16) & 1u);
    return (unsigned short)(u >> 16);
}

__device__ inline unsigned pk2(float lo, float hi) {
    __hip_bfloat162 h = __float22bfloat162_rn(make_float2(lo, hi));
    return *reinterpret_cast<unsigned*>(&h);
}

__device__ inline float bfhi(unsigned u) {
    union { unsigned u; float f; } v; v.u = u & 0xFFFF0000u; return v.f;
}
__device__ inline float bflo(unsigned u) {
    union { unsigned u; float f; } v; v.u = u << 16; return v.f;
}

// ---------------- out0 = ques_feat (exact copy) ----------------
__global__ void k_copy(const float* __restrict__ src, float* __restrict__ dst) {
    int i = blockIdx.x * blockDim.x + threadIdx.x;
    reinterpret_cast<float4*>(dst)[i] = reinterpret_cast<const float4*>(src)[i];
}

// ---------------- WTf: fragment-major packed bf16 of w2x^T ----------------
__global__ void k_pack_w(const float* __restrict__ w, unsigned short* __restrict__ wtf) {
    int kblk = blockIdx.x >> 5;
    int nblk = blockIdx.x & 31;
    int t = threadIdx.x;          // 128: (kc8, col)
    int kc8 = t >> 4, col = t & 15;
    const float* src = w + (size_t)(kblk * 64 + kc8 * 8) * 512 + nblk * 16 + col;
    unsigned short* dst = wtf + (size_t)(kblk * 32 + nblk) * 1024 + kc8 * 128 + col * 8;
    unsigned short tmp[8];
    #pragma unroll
    for (int j = 0; j < 8; ++j) tmp[j] = f2bf(src[(size_t)j * 512]);
    *reinterpret_cast<uint4*>(dst) = *reinterpret_cast<const uint4*>(tmp);
}

// ---------------- cc[b][h] = qf[b]·w2g[:,h] + b2g[h] + b2x[h] ----------------
__global__ void k_cconst(const float* __restrict__ qf, const float* __restrict__ w2g,
                         const float* __restrict__ b2g, const float* __restrict__ b2x,
                         float* __restrict__ cc) {
    __shared__ float qls[2][1024];
    int b0 = blockIdx.x * 2;
    int t = threadIdx.x;
    #pragma unroll
    for (int j = 0; j < 2; ++j) {
        int idx = j * 256 + t;
        int bb = idx >> 8, c4 = idx & 255;
        float4 v = reinterpret_cast<const float4*>(qf + (size_t)(b0 + bb) * 1024)[c4];
        qls[bb][c4 * 4 + 0] = v.x; qls[bb][c4 * 4 + 1] = v.y;
        qls[bb][c4 * 4 + 2] = v.z; qls[bb][c4 * 4 + 3] = v.w;
    }
    __syncthreads();
    float a00 = 0.f, a01 = 0.f, a10 = 0.f, a11 = 0.f;
    #pragma unroll 8
    for (int q = 0; q < 1024; ++q) {
        float w0 = w2g[q * 512 + t];
        float w1 = w2g[q * 512 + 256 + t];
        float q0 = qls[0][q], q1 = qls[1][q];
        a00 += q0 * w0; a01 += q0 * w1;
        a10 += q1 * w0; a11 += q1 * w1;
    }
    float c0 = b2g[t] + b2x[t];
    float c1 = b2g[t + 256] + b2x[t + 256];
    cc[(size_t)b0 * 512 + t] = a00 + c0;
    cc[(size_t)b0 * 512 + t + 256] = a01 + c1;
    cc[(size_t)(b0 + 1) * 512 + t] = a10 + c0;
    cc[(size_t)(b0 + 1) * 512 + t + 256] = a11 + c1;
}

// ---------------- k_convert: X f32 -> swizzled bf16 tile image (128-row tiles) ----------------
// Per (tile, step): 16KB chunk of 1024 granules (16B). Granule g: row=g>>3,
// inner=g&7, holds kins [ ((inner*16)^((row&7)<<4))>>1 .. +8 ). Linear
// global_load_lds of the chunk reproduces the XOR-swizzled LDS tile.
__global__ __launch_bounds__(512) void k_convert(const float* __restrict__ X,
                                                 unsigned short* __restrict__ Xbf) {
    int tile = blockIdx.x;
    int t = threadIdx.x;
    int row = t >> 2;                 // 2 granules per thread share a row
    int in0 = (2 * t) & 7;
    int kin0 = ((in0 * 16) ^ ((row & 7) << 4)) >> 1;
    int kin1 = (((in0 + 1) * 16) ^ ((row & 7) << 4)) >> 1;
    const float* src = X + ((size_t)tile * 128 + row) * 2048;
    unsigned short* dst = Xbf + (size_t)tile * 262144 + t * 16;
    #pragma unroll 4
    for (int step = 0; step < 32; ++step) {
        const float* s0 = src + step * 64 + kin0;
        const float* s1 = src + step * 64 + kin1;
        float4 a0 = *reinterpret_cast<const float4*>(s0);
        float4 a1 = *reinterpret_cast<const float4*>(s0 + 4);
        float4 b0 = *reinterpret_cast<const float4*>(s1);
        float4 b1 = *reinterpret_cast<const float4*>(s1 + 4);
        uint4 o0, o1;
        o0.x = pk2(a0.x, a0.y); o0.y = pk2(a0.z, a0.w);
        o0.z = pk2(a1.x, a1.y); o0.w = pk2(a1.z, a1.w);
        o1.x = pk2(b0.x, b0.y); o1.y = pk2(b0.z, b0.w);
        o1.z = pk2(b1.x, b1.y); o1.w = pk2(b1.z, b1.w);
        unsigned short* d = dst + (size_t)step * 8192;
        *reinterpret_cast<uint4*>(d) = o0;
        *reinterpret_cast<uint4*>(d + 8) = o1;
    }
}

// ---------------- scores: fused GEMM + tanh + dot(w2h) ----------------
#define NSTEP 32

__global__ __launch_bounds__(512, 2) void k_scores(
    const unsigned short* __restrict__ Xbf, const unsigned short* __restrict__ WTf,
    const float* __restrict__ cc, const float* __restrict__ w2h,
    float* __restrict__ scores)
{
    __shared__ __align__(16) unsigned short A[3][8192];   // 3 x 16KB A-buffers
    __shared__ float slds[128];

    int tid = threadIdx.x;
    int wave = tid >> 6, lane = tid & 63;
    int l15 = lane & 15, l4 = lane >> 4;
    int r0 = blockIdx.x * 128;

    // staging: 2 gloads/thread/step; granules tid and 512+tid
    const unsigned short* xsrc = Xbf + (size_t)blockIdx.x * 262144 + tid * 8;
    unsigned short* lds0 = &A[0][0] + wave * 512;          // + bo/2 + {0, 4096}

    // B fragment bases (two, 4KB apart, so (n,kh) offsets fit 13-bit imm)
    const unsigned short* wb0 = WTf + (size_t)wave * 4096 + l4 * 128 + l15 * 8;

    // A fragment byte offsets (XOR folded); + bo + m*2048
    const char* abase = reinterpret_cast<const char*>(&A[0][0]);
    int axor = (l15 & 7) << 4;
    int aoff0 = l15 * 128 + ((l4 * 16) ^ axor);
    int aoff1 = l15 * 128 + ((64 + l4 * 16) ^ axor);

    if (tid < 128) slds[tid] = 0.0f;

    f32x4 acc[8][4];
    #pragma unroll
    for (int m = 0; m < 8; ++m)
        #pragma unroll
        for (int n = 0; n < 4; ++n) acc[m][n] = (f32x4){0.f, 0.f, 0.f, 0.f};

    bf16x8 brE[8], brO[8];   // [0..3]=kh0 n0..3, [4..7]=kh1 n0..3

    #define GLOAD2(bo, step) do { \
        __builtin_amdgcn_global_load_lds((as1_uint*)(xsrc + (size_t)(step) * 8192), \
            (as3_uint*)(lds0 + ((bo) >> 1)), 16, 0, 0); \
        __builtin_amdgcn_global_load_lds((as1_uint*)(xsrc + (size_t)(step) * 8192 + 4096), \
            (as3_uint*)(lds0 + ((bo) >> 1) + 4096), 16, 0, 0); } while (0)

    #define BLOAD(dst, t) do { \
        const unsigned short* bp = wb0 + (size_t)(t) * 32768; \
        dst[0] = *reinterpret_cast<const bf16x8*>(bp); \
        dst[4] = *reinterpret_cast<const bf16x8*>(bp + 512); \
        dst[1] = *reinterpret_cast<const bf16x8*>(bp + 1024); \
        dst[5] = *reinterpret_cast<const bf16x8*>(bp + 1536); \
        dst[2] = *reinterpret_cast<const bf16x8*>(bp + 2048); \
        dst[6] = *reinterpret_cast<const bf16x8*>(bp + 2560); \
        dst[3] = *reinterpret_cast<const bf16x8*>(bp + 3072); \
        dst[7] = *reinterpret_cast<const bf16x8*>(bp + 3584); } while (0)

    #define MFPH(bo, br) do { \
        __builtin_amdgcn_s_setprio(1); \
        _Pragma("unroll") \
        for (int m = 0; m < 8; ++m) { \
            bf16x8 af0 = *reinterpret_cast<const bf16x8*>(abase + (bo) + m * 2048 + aoff0); \
            bf16x8 af1 = *reinterpret_cast<const bf16x8*>(abase + (bo) + m * 2048 + aoff1); \
            _Pragma("unroll") \
            for (int n = 0; n < 4; ++n) { \
                acc[m][n] = __builtin_amdgcn_mfma_f32_16x16x32_bf16(af0, br[n], acc[m][n], 0, 0, 0); \
                acc[m][n] = __builtin_amdgcn_mfma_f32_16x16x32_bf16(af1, br[4 + n], acc[m][n], 0, 0, 0); \
            } \
        } \
        __builtin_amdgcn_s_setprio(0); } while (0)

    #define SBAR __builtin_amdgcn_sched_barrier(0)

    // prologue: DMA steps 0,1; B(0); force DMA(0) retired (leaves DMA(1)+B(0))
    GLOAD2(0, 0);
    GLOAD2(16384, 1);
    BLOAD(brE, 0);
    asm volatile("s_waitcnt vmcnt(10)" ::: "memory");
    __builtin_amdgcn_s_barrier();

    int boE = 0, boO = 16384, boT = 32768;

    #pragma unroll 1
    for (int t2 = 0; t2 < 29; t2 += 2) {
        // ---- even step e = t2 : compute boE with brE ----
        BLOAD(brO, t2 + 1);
        SBAR;
        MFPH(boE, brE);
        SBAR;
        GLOAD2(boT, t2 + 2);
        // retire exactly DMA(t2+1); keep B(t2+1)[8] + DMA(t2+2)[2] in flight
        asm volatile("s_waitcnt vmcnt(10)" ::: "memory");
        SBAR;
        __builtin_amdgcn_s_barrier();
        // ---- odd step o = t2+1 : compute boO with brO ----
        BLOAD(brE, t2 + 2);
        SBAR;
        MFPH(boO, brO);
        SBAR;
        GLOAD2(boE, t2 + 3);       // boE free: all waves passed the even barrier
        asm volatile("s_waitcnt vmcnt(10)" ::: "memory");
        SBAR;
        __builtin_amdgcn_s_barrier();
        // rotate buffers: next (E,O,T) = (T,E,O)
        int tmp = boT; boT = boO; boO = boE; boE = tmp;
    }
    // tail: steps 30, 31 (boE = buf(0), boO = buf(1) after 15 rotations)
    {
        BLOAD(brO, 31);
        SBAR;
        MFPH(boE, brE);
        SBAR;
        asm volatile("s_waitcnt vmcnt(8)" ::: "memory");   // force DMA(31)
        SBAR;
        __builtin_amdgcn_s_barrier();
        MFPH(boO, brO);
    }

    // fence: keep epilogue constant loads out of the K-loop
    asm volatile("" ::: "memory");

    // epilogue: score[row] = sum_h tanh(feat + cc[b(row)][h]) * w2h[h]
    int b0 = r0 / 196;
    int sbreak = (b0 + 1) * 196 - r0;
    int b1 = b0 + 1; if (b1 > 511) b1 = 511;
    float cch0[4], cch1[4], whv[4];
    #pragma unroll
    for (int n = 0; n < 4; ++n) {
        int h = wave * 64 + n * 16 + l15;
        cch0[n] = cc[(size_t)b0 * 512 + h];
        cch1[n] = cc[(size_t)b1 * 512 + h];
        whv[n] = w2h[h];
    }
    #pragma unroll
    for (int m = 0; m < 8; ++m) {
        #pragma unroll
        for (int i = 0; i < 4; ++i) {
            int row = m * 16 + l4 * 4 + i;
            float p = 0.0f;
            #pragma unroll
            for (int n = 0; n < 4; ++n) {
                float x = acc[m][n][i] + ((row < sbreak) ? cch0[n] : cch1[n]);
                float th = 1.0f - 2.0f / (__expf(2.0f * x) + 1.0f);
                p += th * whv[n];
            }
            p += __shfl_xor(p, 1);
            p += __shfl_xor(p, 2);
            p += __shfl_xor(p, 4);
            p += __shfl_xor(p, 8);
            if (l15 == 0) atomicAdd(&slds[row], p);
        }
    }
    __syncthreads();
    if (tid < 128) scores[(size_t)r0 + tid] = slds[tid];
}

// ---------------- softmax over s (196) per b ----------------
__global__ void k_softmax(float* sc) {
    int b = blockIdx.x, t = threadIdx.x;
    __shared__ float red[8];
    float v = (t < 196) ? sc[(size_t)b * 196 + t] : -3.0e38f;
    float m = v;
    for (int o = 32; o > 0; o >>= 1) m = fmaxf(m, __shfl_xor(m, o));
    if ((t & 63) == 0) red[t >> 6] = m;
    __syncthreads();
    m = fmaxf(fmaxf(red[0], red[1]), fmaxf(red[2], red[3]));
    float e = (t < 196) ? __expf(v - m) : 0.0f;
    float s = e;
    for (int o = 32; o > 0; o >>= 1) s += __shfl_xor(s, o);
    if ((t & 63) == 0) red[4 + (t >> 6)] = s;
    __syncthreads();
    float tot = red[4] + red[5] + red[6] + red[7];
    if (t < 196) sc[(size_t)b * 196 + t] = e / tot;
}

// ---------------- wsum from swizzled Xbf (128-row tiles) ----------------
__global__ __launch_bounds__(256) void k_wsum_bf(const unsigned short* __restrict__ Xbf,
                                                 const float* __restrict__ a,
                                                 float* __restrict__ out1) {
    __shared__ float als[196];
    int b = blockIdx.x >> 1;
    int half = blockIdx.x & 1;
    int t = threadIdx.x;
    if (t < 196) als[t] = a[(size_t)b * 196 + t];
    __syncthreads();
    int f = half * 1024 + t * 4;
    int step = f >> 6;
    int kin = f & 63;                 // multiple of 4
    const char* xb = reinterpret_cast<const char*>(Xbf);
    float a0 = 0.f, a1 = 0.f, a2 = 0.f, a3 = 0.f;
    int r = b * 196;
    #pragma unroll 4
    for (int s = 0; s < 196; ++s, ++r) {
        int tile = r >> 7, row = r & 127;
        size_t byte = (size_t)tile * 524288 + (size_t)step * 16384 + row * 128
                      + ((kin * 2) ^ ((row & 7) << 4));
        uint2 v = *reinterpret_cast<const uint2*>(xb + byte);
        float w = als[s];
        a0 += w * bflo(v.x); a1 += w * bfhi(v.x);
        a2 += w * bflo(v.y); a3 += w * bfhi(v.y);
    }
    float4 o = {a0, a1, a2, a3};
    *reinterpret_cast<float4*>(out1 + (size_t)b * 2048 + f) = o;
}

// ======== fallback path (ws too small for Xbf): r5-style f32 kernels ========
__global__ __launch_bounds__(512, 4) void k_scores_f32(
    const float* __restrict__ X, const unsigned short* __restrict__ WTf,
    const float* __restrict__ cc, const float* __restrict__ w2h,
    float* __restrict__ scores)
{
    __shared__ __align__(16) unsigned short A[2][4096];
    __shared__ float slds[64];
    int tid = threadIdx.x;
    int wave = tid >> 6, lane = tid & 63;
    int l15 = lane & 15, l4 = lane >> 4;
    int r0 = blockIdx.x * 64;
    int srow = tid >> 3, sc8 = tid & 7;
    const float* xsrc = X + (size_t)(r0 + srow) * 2048 + sc8 * 8;
    char* abase = reinterpret_cast<char*>(&A[0][0]);
    int sbyte = srow * 128 + ((sc8 * 16) ^ ((srow & 7) << 4));
    const unsigned short* wbase = WTf + (size_t)wave * 4096 + l4 * 128 + l15 * 8;
    int axor = (l15 & 7) << 4;
    int aoff0 = l15 * 128 + ((l4 * 16) ^ axor);
    int aoff1 = l15 * 128 + ((64 + l4 * 16) ^ axor);
    if (tid < 64) slds[tid] = 0.0f;
    f32x4 acc[4][4];
    #pragma unroll
    for (int m = 0; m < 4; ++m)
        #pragma unroll
        for (int n = 0; n < 4; ++n) acc[m][n] = (f32x4){0.f, 0.f, 0.f, 0.f};
    float4 xa0, xa1, xb0, xb1;
    #define XLOADF(d0, d1, t) do { \
        d0 = *reinterpret_cast<const float4*>(xsrc + (t) * 64); \
        d1 = *reinterpret_cast<const float4*>(xsrc + (t) * 64 + 4); } while (0)
    #define STAGEF(buf, v0, v1) do { uint4 o; \
        o.x = pk2(v0.x, v0.y); o.y = pk2(v0.z, v0.w); \
        o.z = pk2(v1.x, v1.y); o.w = pk2(v1.z, v1.w); \
        *reinterpret_cast<uint4*>(abase + (buf) * 8192 + sbyte) = o; } while (0)
    #define COMPUTEF(t, buf) do { \
        const unsigned short* base = wbase + (size_t)(t) * 32768; \
        _Pragma("unroll") \
        for (int kh = 0; kh < 2; ++kh) { \
            bf16x8 br[4]; \
            _Pragma("unroll") \
            for (int n = 0; n < 4; ++n) \
                br[n] = *reinterpret_cast<const bf16x8*>(base + n * 1024 + kh * 512); \
            int aoffk = kh ? aoff1 : aoff0; \
            _Pragma("unroll") \
            for (int m = 0; m < 4; ++m) { \
                bf16x8 af = *reinterpret_cast<const bf16x8*>( \
                    abase + (buf) * 8192 + m * 2048 + aoffk); \
                _Pragma("unroll") \
                for (int n = 0; n < 4; ++n) \
                    acc[m][n] = __builtin_amdgcn_mfma_f32_16x16x32_bf16(af, br[n], acc[m][n], 0, 0, 0); \
            } \
        } } while (0)
    XLOADF(xa0, xa1, 0);
    XLOADF(xb0, xb1, 1);
    STAGEF(0, xa0, xa1);
    __syncthreads();
    #pragma unroll 1
    for (int t2 = 0; t2 < NSTEP; t2 += 2) {
        if (t2 + 2 < NSTEP) XLOADF(xa0, xa1, t2 + 2);
        COMPUTEF(t2, 0);
        STAGEF(1, xb0, xb1);
        __syncthreads();
        if (t2 + 3 < NSTEP) XLOADF(xb0, xb1, t2 + 3);
        COMPUTEF(t2 + 1, 1);
        if (t2 + 2 < NSTEP) { STAGEF(0, xa0, xa1); __syncthreads(); }
    }
    asm volatile("" ::: "memory");
    int b0 = r0 / 196;
    int sbreak = (b0 + 1) * 196 - r0;
    int b1 = b0 + 1; if (b1 > 511) b1 = 511;
    float cch0[4], cch1[4], whv[4];
    #pragma unroll
    for (int n = 0; n < 4; ++n) {
        int h = wave * 64 + n * 16 + l15;
        cch0[n] = cc[(size_t)b0 * 512 + h];
        cch1[n] = cc[(size_t)b1 * 512 + h];
        whv[n] = w2h[h];
    }
    #pragma unroll
    for (int m = 0; m < 4; ++m) {
        #pragma unroll
        for (int i = 0; i < 4; ++i) {
            int row = m * 16 + l4 * 4 + i;
            float p = 0.0f;
            #pragma unroll
            for (int n = 0; n < 4; ++n) {
                float x = acc[m][n][i] + ((row < sbreak) ? cch0[n] : cch1[n]);
                float th = 1.0f - 2.0f / (__expf(2.0f * x) + 1.0f);
                p += th * whv[n];
            }
            p += __shfl_xor(p, 1);
            p += __shfl_xor(p, 2);
            p += __shfl_xor(p, 4);
            p += __shfl_xor(p, 8);
            if (l15 == 0) atomicAdd(&slds[row], p);
        }
    }
    __syncthreads();
    if (tid < 64) scores[(size_t)r0 + tid] = slds[tid];
}

__global__ void k_wsum_f32(const float* __restrict__ X, const float* __restrict__ a,
                           float* __restrict__ out1) {
    __shared__ float als[196];
    int b = blockIdx.x >> 1;
    int fh = (blockIdx.x & 1) * 1024;
    int t = threadIdx.x;
    if (t < 196) als[t] = a[(size_t)b * 196 + t];
    __syncthreads();
    int f = fh + t * 4;
    const float* Xb = X + (size_t)b * 196 * 2048 + f;
    float4 acc = {0.f, 0.f, 0.f, 0.f};
    #pragma unroll 4
    for (int s = 0; s < 196; ++s) {
        float4 x = *reinterpret_cast<const float4*>(Xb + (size_t)s * 2048);
        float w = als[s];
        acc.x += w * x.x; acc.y += w * x.y; acc.z += w * x.z; acc.w += w * x.w;
    }
    *reinterpret_cast<float4*>(out1 + (size_t)b * 2048 + f) = acc;
}

extern "C" void kernel_launch(void* const* d_in, const int* in_sizes, int n_in,
                              void* d_out, int out_size, void* d_ws, size_t ws_size,
                              hipStream_t stream) {
    const float* qf  = (const float*)d_in[0];
    const float* X   = (const float*)d_in[1];
    const float* w2x = (const float*)d_in[6];
    const float* b2x = (const float*)d_in[7];
    const float* w2g = (const float*)d_in[8];
    const float* b2g = (const float*)d_in[9];
    const float* w2h = (const float*)d_in[10];

    float* out0 = (float*)d_out;                 // ques_attn = ques_feat (512x1024)
    float* out1 = out0 + 512 * 1024;             // img_attn (512x2048)

    // ws layout: [0,2MB) WTf; [2MB,3MB) cc; [3MB,4MB) scores flat [100352]; [4MB,..) Xbf
    unsigned short* WTf = (unsigned short*)d_ws;
    float* cc = (float*)((char*)d_ws + (size_t)(2u << 20));
    float* sc = (float*)((char*)d_ws + (size_t)(3u << 20));
    unsigned short* xbf = (unsigned short*)((char*)d_ws + (size_t)(4u << 20));
    const size_t XBF_BYTES = (size_t)784 * 524288;   // 411 MB
    int big = (ws_size >= (size_t)(4u << 20) + XBF_BYTES) ? 1 : 0;

    k_copy<<<512, 256, 0, stream>>>(qf, out0);
    k_pack_w<<<1024, 128, 0, stream>>>(w2x, WTf);
    k_cconst<<<256, 256, 0, stream>>>(qf, w2g, b2g, b2x, cc);
    if (big) {
        k_convert<<<784, 512, 0, stream>>>(X, xbf);
        k_scores<<<784, 512, 0, stream>>>(xbf, WTf, cc, w2h, sc);
        k_softmax<<<512, 256, 0, stream>>>(sc);
        k_wsum_bf<<<1024, 256, 0, stream>>>(xbf, sc, out1);
    } else {
        k_scores_f32<<<1568, 512, 0, stream>>>(X, WTf, cc, w2h, sc);
        k_softmax<<<512, 256, 0, stream>>>(sc);
        k_wsum_f32<<<1024, 256, 0, stream>>>(X, sc, out1);
    }
}

// Round 9
// 531.099 us; speedup vs baseline: 1.5275x; 1.5275x over previous
//
#include <hip/hip_runtime.h>
#include <hip/hip_bf16.h>
#include <cstdint>

// Shapes: B=512, S=196, I=2048, Q=1024, H=512
// ques_attn == ques_feat exactly (softmax over singleton axis). Only img_attn computed:
//   cc[b][h]  = sum_q qf[b][q]*w2g[q][h] + b2g[h] + b2x[h]
//   score[r]  = sum_h tanh( sum_k X[r][k]*w2x[k][h] + cc[b(r)][h] ) * w2h[h]   (r = b*196+s)
//   a = softmax_s(score);  img_attn[b][f] = sum_s a[b][s] * X[b][s][f]
//
// r9: NO convert pass. k_scores stages f32 X straight into LDS via global_load_lds
// with a pre-swizzled per-lane GLOBAL source (pc = gcol ^ (row&15), an involution;
// conflict-free for both DMA write and frag read), converts to bf16 at the LDS->reg
// step with v_cvt_pk_bf16_f32. r7's proven 4-buffer distance-3 pipeline, raw
// s_barrier, no drains. X DMA uses aux=2 (NT) so the 822MB stream doesn't evict
// the 2MB WTf B-panel from L2 (B re-reads = 3.2GB/pass, the throughput tax).

typedef __attribute__((ext_vector_type(8))) short bf16x8;
typedef __attribute__((ext_vector_type(4))) float f32x4;

typedef __attribute__((address_space(1))) const unsigned int as1_uint;
typedef __attribute__((address_space(3))) unsigned int as3_uint;

__device__ inline unsigned short f2bf(float f) {
    union { float f; unsigned u; } v; v.f = f;
    unsigned u = v.u;
    u += 0x7FFFu + ((u >> 16) & 1u);
    return (unsigned short)(u >> 16);
}

__device__ inline unsigned pk2(float lo, float hi) {
    __hip_bfloat162 h = __float22bfloat162_rn(make_float2(lo, hi));
    return *reinterpret_cast<unsigned*>(&h);
}

// 8 f32 (two uint4) -> bf16x8 via v_cvt_pk_bf16_f32
__device__ inline bf16x8 cvt8(uint4 lo, uint4 hi) {
    union { uint4 q; float f[4]; } a, b; a.q = lo; b.q = hi;
    union { unsigned u[4]; bf16x8 v; } r;
    r.u[0] = pk2(a.f[0], a.f[1]); r.u[1] = pk2(a.f[2], a.f[3]);
    r.u[2] = pk2(b.f[0], b.f[1]); r.u[3] = pk2(b.f[2], b.f[3]);
    return r.v;
}

// ---------------- out0 = ques_feat (exact copy) ----------------
__global__ void k_copy(const float* __restrict__ src, float* __restrict__ dst) {
    int i = blockIdx.x * blockDim.x + threadIdx.x;
    reinterpret_cast<float4*>(dst)[i] = reinterpret_cast<const float4*>(src)[i];
}

// ---------------- WTf: fragment-major packed bf16 of w2x^T ----------------
// Tile (kblk, nblk) = 64 k x 16 cols: [kc8 0..7][col 0..15][j 0..7];
// a wave's B-fragment read (16 cols x 32 k) is one contiguous 1 KB access.
__global__ void k_pack_w(const float* __restrict__ w, unsigned short* __restrict__ wtf) {
    int kblk = blockIdx.x >> 5;
    int nblk = blockIdx.x & 31;
    int t = threadIdx.x;          // 128: (kc8, col)
    int kc8 = t >> 4, col = t & 15;
    const float* src = w + (size_t)(kblk * 64 + kc8 * 8) * 512 + nblk * 16 + col;
    unsigned short* dst = wtf + (size_t)(kblk * 32 + nblk) * 1024 + kc8 * 128 + col * 8;
    unsigned short tmp[8];
    #pragma unroll
    for (int j = 0; j < 8; ++j) tmp[j] = f2bf(src[(size_t)j * 512]);
    *reinterpret_cast<uint4*>(dst) = *reinterpret_cast<const uint4*>(tmp);
}

// ---------------- cc[b][h] = qf[b]·w2g[:,h] + b2g[h] + b2x[h] ----------------
__global__ void k_cconst(const float* __restrict__ qf, const float* __restrict__ w2g,
                         const float* __restrict__ b2g, const float* __restrict__ b2x,
                         float* __restrict__ cc) {
    __shared__ float qls[2][1024];
    int b0 = blockIdx.x * 2;
    int t = threadIdx.x;
    #pragma unroll
    for (int j = 0; j < 2; ++j) {
        int idx = j * 256 + t;
        int bb = idx >> 8, c4 = idx & 255;
        float4 v = reinterpret_cast<const float4*>(qf + (size_t)(b0 + bb) * 1024)[c4];
        qls[bb][c4 * 4 + 0] = v.x; qls[bb][c4 * 4 + 1] = v.y;
        qls[bb][c4 * 4 + 2] = v.z; qls[bb][c4 * 4 + 3] = v.w;
    }
    __syncthreads();
    float a00 = 0.f, a01 = 0.f, a10 = 0.f, a11 = 0.f;
    #pragma unroll 8
    for (int q = 0; q < 1024; ++q) {
        float w0 = w2g[q * 512 + t];
        float w1 = w2g[q * 512 + 256 + t];
        float q0 = qls[0][q], q1 = qls[1][q];
        a00 += q0 * w0; a01 += q0 * w1;
        a10 += q1 * w0; a11 += q1 * w1;
    }
    float c0 = b2g[t] + b2x[t];
    float c1 = b2g[t + 256] + b2x[t + 256];
    cc[(size_t)b0 * 512 + t] = a00 + c0;
    cc[(size_t)b0 * 512 + t + 256] = a01 + c1;
    cc[(size_t)(b0 + 1) * 512 + t] = a10 + c0;
    cc[(size_t)(b0 + 1) * 512 + t + 256] = a11 + c1;
}

// ---------------- scores: fused GEMM + tanh + dot(w2h), f32-X direct ----------------
// grid 1568 M-tiles of 64 rows; block 512 = 8 waves, wave owns 64 cols (acc 64 AGPR).
// K-step 64. A staged as f32: per step 64 rows x 64 f32 = 16KB = 1024 granules(16B).
// Granule at LDS pos p (=row*16+pc): content f32 col-group gcol = pc ^ (row&15)
// (involution) -> DMA dest linear (wave-uniform+lane*16), per-lane swizzled SOURCE.
// Frag read: two ds_read_b128 at pc=(kh*8+l4*2+h)^l15 -> conflict-free (all 32 banks).
#define NSTEP 32

__global__ __launch_bounds__(512, 4) void k_scores(
    const float* __restrict__ X, const unsigned short* __restrict__ WTf,
    const float* __restrict__ cc, const float* __restrict__ w2h,
    float* __restrict__ scores)
{
    __shared__ __align__(16) char Ab[4][16384];   // 4 x 16KB f32 A-buffers
    __shared__ float slds[64];

    int tid = threadIdx.x;
    int wave = tid >> 6, lane = tid & 63;
    int l15 = lane & 15, l4 = lane >> 4;
    int r0 = blockIdx.x * 64;

    // staging: thread t stages granules t (rows 0..31) and t+512 (rows 32..63)
    int srow = tid >> 4, spc = tid & 15;
    const char* xsrc = reinterpret_cast<const char*>(X + (size_t)(r0 + srow) * 2048)
                       + ((spc ^ (srow & 15)) << 4);
    const char* xsrc2 = xsrc + (size_t)32 * 8192;   // row+32: same (row&15) -> same swizzle
    char* ldsw = &Ab[0][0] + wave * 1024;           // + bufofs (+8192 for 2nd granule)

    // B fragment base; (n,kh) offsets are immediates off bp
    const unsigned short* wb0 = WTf + (size_t)wave * 4096 + l4 * 128 + l15 * 8;

    // A fragment byte voffsets: l15*256 + (( kh*8 + l4*2 + h ) ^ l15)*16
    const char* abase = &Ab[0][0];
    int off00 = l15 * 256 + (((l4 * 2 + 0) ^ l15) << 4);
    int off01 = l15 * 256 + (((l4 * 2 + 1) ^ l15) << 4);
    int off10 = l15 * 256 + (((8 + l4 * 2 + 0) ^ l15) << 4);
    int off11 = l15 * 256 + (((8 + l4 * 2 + 1) ^ l15) << 4);

    if (tid < 64) slds[tid] = 0.0f;

    f32x4 acc[4][4];
    #pragma unroll
    for (int m = 0; m < 4; ++m)
        #pragma unroll
        for (int n = 0; n < 4; ++n) acc[m][n] = (f32x4){0.f, 0.f, 0.f, 0.f};

    bf16x8 brA[4], brB[4];

    // aux=2 (NT): X is a pure stream; don't evict the L2-hot WTf panel
    #define GLOAD2(bufofs, step) do { \
        __builtin_amdgcn_global_load_lds((as1_uint*)(xsrc + (step) * 256), \
            (as3_uint*)(ldsw + (bufofs)), 16, 0, 2); \
        __builtin_amdgcn_global_load_lds((as1_uint*)(xsrc2 + (step) * 256), \
            (as3_uint*)(ldsw + (bufofs) + 8192), 16, 0, 2); } while (0)

    #define BLOAD(dst, t, kh) do { \
        const unsigned short* bp = wb0 + (size_t)(t) * 32768 + (kh) * 512; \
        dst[0] = *reinterpret_cast<const bf16x8*>(bp); \
        dst[1] = *reinterpret_cast<const bf16x8*>(bp + 1024); \
        dst[2] = *reinterpret_cast<const bf16x8*>(bp + 2048); \
        dst[3] = *reinterpret_cast<const bf16x8*>(bp + 3072); } while (0)

    #define MF(br, bufofs, offL, offH) do { \
        __builtin_amdgcn_s_setprio(1); \
        _Pragma("unroll") \
        for (int m = 0; m < 4; ++m) { \
            uint4 lo = *reinterpret_cast<const uint4*>(abase + (bufofs) + m * 4096 + (offL)); \
            uint4 hi = *reinterpret_cast<const uint4*>(abase + (bufofs) + m * 4096 + (offH)); \
            bf16x8 af = cvt8(lo, hi); \
            _Pragma("unroll") \
            for (int n = 0; n < 4; ++n) \
                acc[m][n] = __builtin_amdgcn_mfma_f32_16x16x32_bf16(af, br[n], acc[m][n], 0, 0, 0); \
        } \
        __builtin_amdgcn_s_setprio(0); } while (0)

    #define SBAR __builtin_amdgcn_sched_barrier(0)

    // prologue: fill DMA pipeline 3 deep; retire exactly DMA(0) (6 dma + 8 B out)
    GLOAD2(0, 0);
    GLOAD2(16384, 1);
    GLOAD2(32768, 2);
    BLOAD(brA, 0, 0);
    asm volatile("s_waitcnt vmcnt(12)" ::: "memory");
    __builtin_amdgcn_s_barrier();

    // steady state: wait-for-brB(t-1) at step t-1 transitively retires DMA(t)
    // (issued step t-3, older) before barrier(t-1) -> buf t safe at step t.
    #pragma unroll 1
    for (int t = 0; t < NSTEP; ++t) {
        int bufofs = (t & 3) * 16384;
        BLOAD(brB, t, 1);
        MF(brA, bufofs, off00, off01);
        if (t + 1 < NSTEP) BLOAD(brA, t + 1, 0);
        MF(brB, bufofs, off10, off11);
        SBAR;
        if (t + 3 < NSTEP) GLOAD2(((t + 3) & 3) * 16384, t + 3);
        SBAR;
        __builtin_amdgcn_s_barrier();
    }

    // fence: keep epilogue constant loads out of the K-loop
    asm volatile("" ::: "memory");

    // epilogue: score[row] = sum_h tanh(feat + cc[b(row)][h]) * w2h[h]
    int b0 = r0 / 196;
    int sbreak = (b0 + 1) * 196 - r0;
    int b1 = b0 + 1; if (b1 > 511) b1 = 511;
    float cch0[4], cch1[4], whv[4];
    #pragma unroll
    for (int n = 0; n < 4; ++n) {
        int h = wave * 64 + n * 16 + l15;
        cch0[n] = cc[(size_t)b0 * 512 + h];
        cch1[n] = cc[(size_t)b1 * 512 + h];
        whv[n] = w2h[h];
    }
    #pragma unroll
    for (int m = 0; m < 4; ++m) {
        #pragma unroll
        for (int i = 0; i < 4; ++i) {
            int row = m * 16 + l4 * 4 + i;
            float p = 0.0f;
            #pragma unroll
            for (int n = 0; n < 4; ++n) {
                float x = acc[m][n][i] + ((row < sbreak) ? cch0[n] : cch1[n]);
                float th = 1.0f - 2.0f / (__expf(2.0f * x) + 1.0f);
                p += th * whv[n];
            }
            p += __shfl_xor(p, 1);
            p += __shfl_xor(p, 2);
            p += __shfl_xor(p, 4);
            p += __shfl_xor(p, 8);
            if (l15 == 0) atomicAdd(&slds[row], p);
        }
    }
    __syncthreads();
    if (tid < 64) scores[(size_t)r0 + tid] = slds[tid];
}

// ---------------- softmax over s (196) per b ----------------
__global__ void k_softmax(float* sc) {
    int b = blockIdx.x, t = threadIdx.x;
    __shared__ float red[8];
    float v = (t < 196) ? sc[(size_t)b * 196 + t] : -3.0e38f;
    float m = v;
    for (int o = 32; o > 0; o >>= 1) m = fmaxf(m, __shfl_xor(m, o));
    if ((t & 63) == 0) red[t >> 6] = m;
    __syncthreads();
    m = fmaxf(fmaxf(red[0], red[1]), fmaxf(red[2], red[3]));
    float e = (t < 196) ? __expf(v - m) : 0.0f;
    float s = e;
    for (int o = 32; o > 0; o >>= 1) s += __shfl_xor(s, o);
    if ((t & 63) == 0) red[4 + (t >> 6)] = s;
    __syncthreads();
    float tot = red[4] + red[5] + red[6] + red[7];
    if (t < 196) sc[(size_t)b * 196 + t] = e / tot;
}

// ---------------- img_attn[b][f] = sum_s a[b][s] * X[b][s][f] ----------------
__global__ void k_wsum(const float* __restrict__ X, const float* __restrict__ a,
                       float* __restrict__ out1) {
    __shared__ float als[196];
    int b = blockIdx.x >> 1;
    int fh = (blockIdx.x & 1) * 1024;
    int t = threadIdx.x;
    if (t < 196) als[t] = a[(size_t)b * 196 + t];
    __syncthreads();
    int f = fh + t * 4;
    const float* Xb = X + (size_t)b * 196 * 2048 + f;
    float4 acc = {0.f, 0.f, 0.f, 0.f};
    #pragma unroll 4
    for (int s = 0; s < 196; ++s) {
        float4 x = *reinterpret_cast<const float4*>(Xb + (size_t)s * 2048);
        float w = als[s];
        acc.x += w * x.x; acc.y += w * x.y; acc.z += w * x.z; acc.w += w * x.w;
    }
    *reinterpret_cast<float4*>(out1 + (size_t)b * 2048 + f) = acc;
}

extern "C" void kernel_launch(void* const* d_in, const int* in_sizes, int n_in,
                              void* d_out, int out_size, void* d_ws, size_t ws_size,
                              hipStream_t stream) {
    const float* qf  = (const float*)d_in[0];
    const float* X   = (const float*)d_in[1];
    const float* w2x = (const float*)d_in[6];
    const float* b2x = (const float*)d_in[7];
    const float* w2g = (const float*)d_in[8];
    const float* b2g = (const float*)d_in[9];
    const float* w2h = (const float*)d_in[10];

    float* out0 = (float*)d_out;                 // ques_attn = ques_feat (512x1024)
    float* out1 = out0 + 512 * 1024;             // img_attn (512x2048)

    // ws layout: [0,2MB) WTf bf16 packed; [2MB,3MB) cc f32; [3MB,..) scores f32 flat [100352]
    unsigned short* WTf = (unsigned short*)d_ws;
    float* cc = (float*)((char*)d_ws + (size_t)(2u << 20));
    float* sc = (float*)((char*)d_ws + (size_t)(3u << 20));

    k_copy<<<512, 256, 0, stream>>>(qf, out0);
    k_pack_w<<<1024, 128, 0, stream>>>(w2x, WTf);
    k_cconst<<<256, 256, 0, stream>>>(qf, w2g, b2g, b2x, cc);
    k_scores<<<1568, 512, 0, stream>>>(X, WTf, cc, w2h, sc);
    k_softmax<<<512, 256, 0, stream>>>(sc);
    k_wsum<<<1024, 256, 0, stream>>>(X, sc, out1);
}